// Round 3
// baseline (884.542 us; speedup 1.0000x reference)
//
#include <hip/hip_runtime.h>
#include <math.h>

// Problem constants
#define KCL   8192      // clusters
#define DIM   64        // embedding dim
#define NPTS  32768     // B*H*W
#define HW    1024      // H*W
#define PLANE 65536     // D*H*W (per-batch stride in z)
#define CCH   128       // clusters per chunk
#define NCH   (KCL/CCH) // 64 chunks
#define TP    16        // points per wave (wave-uniform)
#define TC    2         // clusters per lane

// -------------------- e2[k] = ||embedding[k]||^2 --------------------
__global__ __launch_bounds__(256) void e2_kernel(const float* __restrict__ emb,
                                                 float* __restrict__ e2) {
    int k = blockIdx.x * 256 + threadIdx.x;
    const float4* row = (const float4*)(emb + (size_t)k * DIM);
    float s = 0.f;
#pragma unroll
    for (int i = 0; i < DIM / 4; ++i) {
        float4 v = row[i];
        s += v.x * v.x + v.y * v.y + v.z * v.z + v.w * v.w;
    }
    e2[k] = s;
}

// -------------------- main fused kernel --------------------
// Block: 64 points. Wave w owns points 16w..16w+15 (wave-uniform z via scalar
// loads). Lanes split each 128-cluster chunk: lane owns clusters {2*lane, 2*lane+1}.
// e-chunks double-buffered in LDS, rows XOR-swizzled for conflict-free row-gather.
#define FMA4(zz, ib) \
    acc[ib+0][0]=fmaf(zz.x,e0,acc[ib+0][0]); acc[ib+0][1]=fmaf(zz.x,e1,acc[ib+0][1]); \
    acc[ib+1][0]=fmaf(zz.y,e0,acc[ib+1][0]); acc[ib+1][1]=fmaf(zz.y,e1,acc[ib+1][1]); \
    acc[ib+2][0]=fmaf(zz.z,e0,acc[ib+2][0]); acc[ib+2][1]=fmaf(zz.z,e1,acc[ib+2][1]); \
    acc[ib+3][0]=fmaf(zz.w,e0,acc[ib+3][0]); acc[ib+3][1]=fmaf(zz.w,e1,acc[ib+3][1]);

__global__ __launch_bounds__(256, 2) void vq_main(
    const float* __restrict__ z, const float* __restrict__ emb,
    const float* __restrict__ e2g, float* __restrict__ counts,
    float* __restrict__ bavg, float* __restrict__ loss_ws,
    float* __restrict__ zq_out, float* __restrict__ idx_out) {

    __shared__ __align__(16) float ebuf[2][CCH * DIM];  // 2 x 32KB, swizzled rows
    __shared__ float e2buf[2][CCH];
    __shared__ int   kbest_lds[64];

    const int t    = threadIdx.x;
    const int lane = t & 63;
    const int wuni = __builtin_amdgcn_readfirstlane(t >> 6);  // wave id 0..3
    const int p0   = blockIdx.x * 64;
    const int b    = p0 >> 10;
    const int hw0  = p0 & 1023;

    // wave-uniform z base: points 16*wuni .. +15 of this block (z is [d][hw])
    const float* zw = z + (size_t)b * PLANE + hw0 + 16 * wuni;

    // staging geometry: thread t stages row (t>>1), slots (t&1)*8 .. +7
    const int srow  = t >> 1;
    const int sbase = (t & 1) * 8;
    const int skey  = (t >> 3) & 15;           // (srow>>2)&15
    // read geometry: lane reads rows 2*lane, 2*lane+1
    const int rb0 = (2 * lane) * DIM;
    const int rb1 = rb0 + DIM;
    const int sw4 = ((lane >> 1) & 15) << 2;   // swizzle key * 4 floats

    // ---- prologue: stage chunk 0 into buffer 0 ----
    {
        const float* src = emb + (size_t)srow * DIM;
#pragma unroll
        for (int i = 0; i < 8; ++i) {
            int slot = sbase + i;
            float4 v = *(const float4*)(src + slot * 4);
            *(float4*)&ebuf[0][srow * DIM + ((slot ^ skey) << 2)] = v;
        }
        e2buf[0][t & 127] = e2g[t & 127];
    }

    float best[TP]; int bestk[TP];
#pragma unroll
    for (int i = 0; i < TP; ++i) { best[i] = 3.4e38f; bestk[i] = 0; }

    __syncthreads();

    for (int kc = 0; kc < NCH; ++kc) {
        const int cur = kc & 1;
        const int k0  = kc * CCH;

        // T14: issue next chunk's global loads now; write to LDS after compute
        float4 st[8]; float e2st = 0.f;
        const bool more = (kc + 1 < NCH);
        if (more) {
            const float* src = emb + (size_t)(k0 + CCH + srow) * DIM;
#pragma unroll
            for (int i = 0; i < 8; ++i) st[i] = *(const float4*)(src + (sbase + i) * 4);
            e2st = e2g[k0 + CCH + (t & 127)];
        }

        float acc[TP][TC];
#pragma unroll
        for (int i = 0; i < TP; ++i) { acc[i][0] = 0.f; acc[i][1] = 0.f; }

        const float* eb = &ebuf[cur][0];
#pragma unroll 4
        for (int dg = 0; dg < 16; ++dg) {
            float4 ea = *(const float4*)&eb[rb0 + ((dg << 2) ^ sw4)];
            float4 ec = *(const float4*)&eb[rb1 + ((dg << 2) ^ sw4)];
#pragma unroll
            for (int dd = 0; dd < 4; ++dd) {
                const float* zd = zw + (size_t)(4 * dg + dd) * HW;
                float4 z0 = *(const float4*)(zd);
                float4 z1 = *(const float4*)(zd + 4);
                float4 z2 = *(const float4*)(zd + 8);
                float4 z3 = *(const float4*)(zd + 12);
                float e0 = (dd == 0) ? ea.x : (dd == 1) ? ea.y : (dd == 2) ? ea.z : ea.w;
                float e1 = (dd == 0) ? ec.x : (dd == 1) ? ec.y : (dd == 2) ? ec.z : ec.w;
                FMA4(z0, 0) FMA4(z1, 4) FMA4(z2, 8) FMA4(z3, 12)
            }
        }

        // distances + running argmin (ascending k, strict < => first-index ties)
#pragma unroll
        for (int i = 0; i < TP; ++i) {
#pragma unroll
            for (int j = 0; j < TC; ++j) {
                float dist = fmaf(-2.f, acc[i][j], e2buf[cur][2 * lane + j]);
                int kk = k0 + 2 * lane + j;
                if (dist < best[i]) { best[i] = dist; bestk[i] = kk; }
            }
        }

        // write staged data into the other buffer, then publish
        if (more) {
#pragma unroll
            for (int i = 0; i < 8; ++i) {
                int slot = sbase + i;
                *(float4*)&ebuf[cur ^ 1][srow * DIM + ((slot ^ skey) << 2)] = st[i];
            }
            e2buf[cur ^ 1][t & 127] = e2st;
        }
        __syncthreads();
    }

    // ---- cross-lane argmin over 64 lanes (first-index tiebreak) ----
#pragma unroll
    for (int i = 0; i < TP; ++i) {
        float bd = best[i]; int bk = bestk[i];
#pragma unroll
        for (int off = 32; off > 0; off >>= 1) {
            float od = __shfl_xor(bd, off);
            int   ok = __shfl_xor(bk, off);
            if (od < bd || (od == bd && ok < bk)) { bd = od; bk = ok; }
        }
        if (lane == 0) {
            int p = 16 * wuni + i;
            kbest_lds[p] = bk;
            idx_out[p0 + p] = (float)bk;
            atomicAdd(&counts[bk], 1.0f);
        }
    }
    __syncthreads();

    // ---- epilogue: p = t&63 (point), q = t>>6 (dim quarter) ----
    {
        const int p = t & 63, q = t >> 6;
        const int k = kbest_lds[p];
        const float* er = emb + (size_t)k * DIM;
        float lsum = 0.f;
#pragma unroll
        for (int dd = 0; dd < 16; ++dd) {
            int d = 16 * q + dd;
            size_t gidx = (size_t)b * PLANE + (size_t)d * HW + hw0 + p;
            float zv = z[gidx];
            float ev = er[d];
            zq_out[gidx] = ev;                       // coalesced (lanes = consecutive p)
            float df = ev - zv; lsum += df * df;
            atomicAdd(&bavg[(size_t)k * DIM + d], zv);
        }
#pragma unroll
        for (int off = 32; off > 0; off >>= 1) lsum += __shfl_xor(lsum, off);
        if (lane == 0) atomicAdd(loss_ws, lsum);
    }
}

// -------------------- EMA finalize: outputs 4,5,6 --------------------
__global__ __launch_bounds__(256) void ema_kernel(
    const float* __restrict__ ema_cs, const float* __restrict__ ema_avg,
    const float* __restrict__ counts, const float* __restrict__ bavg,
    float* __restrict__ out_ncs, float* __restrict__ out_navg,
    float* __restrict__ out_nemb) {
    int tid = blockIdx.x * 256 + threadIdx.x;  // 0..131071 (K*D/4)
    int k = tid >> 4;
    float ncs = 0.99f * ema_cs[k] + 0.01f * counts[k];
    float den = ncs + 1e-5f;
    float4 ea = ((const float4*)ema_avg)[tid];
    float4 ba = ((const float4*)bavg)[tid];
    float4 na, ne;
    na.x = 0.99f * ea.x + 0.01f * ba.x;
    na.y = 0.99f * ea.y + 0.01f * ba.y;
    na.z = 0.99f * ea.z + 0.01f * ba.z;
    na.w = 0.99f * ea.w + 0.01f * ba.w;
    ne.x = na.x / den; ne.y = na.y / den; ne.z = na.z / den; ne.w = na.w / den;
    ((float4*)out_navg)[tid] = na;
    ((float4*)out_nemb)[tid] = ne;
    if ((tid & 15) == 0) out_ncs[k] = ncs;
}

// -------------------- scalars: loss + perplexity --------------------
__global__ __launch_bounds__(256) void scalars_kernel(
    const float* __restrict__ counts, const float* __restrict__ loss_ws,
    float* __restrict__ out_loss, float* __restrict__ out_perp) {
    __shared__ float red[4];
    float s = 0.f;
    for (int k = threadIdx.x; k < KCL; k += 256) {
        float p = counts[k] * (1.0f / (float)NPTS);
        s += p * logf(p + 1e-10f);
    }
#pragma unroll
    for (int off = 32; off > 0; off >>= 1) s += __shfl_xor(s, off, 64);
    if ((threadIdx.x & 63) == 0) red[threadIdx.x >> 6] = s;
    __syncthreads();
    if (threadIdx.x == 0) {
        float tot = red[0] + red[1] + red[2] + red[3];
        out_perp[0] = expf(-tot);
        out_loss[0] = 0.25f * loss_ws[0] / (float)(NPTS * DIM);
    }
}

extern "C" void kernel_launch(void* const* d_in, const int* in_sizes, int n_in,
                              void* d_out, int out_size, void* d_ws, size_t ws_size,
                              hipStream_t stream) {
    (void)in_sizes; (void)n_in; (void)out_size; (void)ws_size;
    const float* z       = (const float*)d_in[0];
    const float* emb     = (const float*)d_in[1];
    const float* ema_cs  = (const float*)d_in[2];
    const float* ema_avg = (const float*)d_in[3];

    float* out0      = (float*)d_out;            // z_quantized_st  [2097152]
    float* out_loss  = out0 + 2097152;           // loss            [1]
    float* out_perp  = out_loss + 1;             // perplexity      [1]
    float* out_idx   = out_perp + 1;             // encoding_indices[32768]
    float* out_nemb  = out_idx + NPTS;           // new_embedding   [524288]
    float* out_ncs   = out_nemb + KCL * DIM;     // new_cluster_size[8192]
    float* out_navg  = out_ncs + KCL;            // new_embedding_avg[524288]

    float* e2_ws     = (float*)d_ws;             // [8192]
    float* counts_ws = e2_ws + KCL;              // [8192]
    float* bavg_ws   = counts_ws + KCL;          // [524288]
    float* loss_ws   = bavg_ws + KCL * DIM;      // [1]

    // zero the accumulators (counts + bavg + loss scalar)
    hipMemsetAsync((void*)counts_ws, 0, (size_t)(KCL + KCL * DIM + 1) * sizeof(float), stream);

    e2_kernel<<<KCL / 256, 256, 0, stream>>>(emb, e2_ws);
    vq_main<<<NPTS / 64, 256, 0, stream>>>(z, emb, e2_ws, counts_ws, bavg_ws,
                                           loss_ws, out0, out_idx);
    ema_kernel<<<KCL * DIM / 4 / 256, 256, 0, stream>>>(ema_cs, ema_avg, counts_ws,
                                                        bavg_ws, out_ncs, out_navg, out_nemb);
    scalars_kernel<<<1, 256, 0, stream>>>(counts_ws, loss_ws, out_loss, out_perp);
}